// Round 2
// baseline (3192.266 us; speedup 1.0000x reference)
//
#include <hip/hip_runtime.h>
#include <cstdint>
#include <cstddef>

// ---------------- problem constants ----------------
#define BB 64
#define LL 196
#define EE 2048
#define AD 512
#define DD 512
#define EM 512
#define VV 10000
#define TTOK 32
#define MT 31
#define KX 3072   /* xfull = [emb 512 | ctx 2048 | h 512] */
#define G4 2048   /* 4*DD */
#define VPAD 10048 /* 157*64 */

// ---------------- output offsets (floats) ----------------
#define OUT_PRED 0
#define OUT_CAPS (BB*MT*VV)
#define OUT_DL   (OUT_CAPS + BB*TTOK)
#define OUT_ALPH (OUT_DL + BB)
#define OUT_SIDX (OUT_ALPH + BB*MT*LL)

// ---------------- workspace offsets (floats, all 64-aligned) ----------------
// IDENTICAL to the 2990us-verified session layout (gacc back to 1x, atomic scheme).
#define OFF_SIDX 0
#define OFF_DL   64
#define OFF_MEAN 128
#define OFF_C    (OFF_MEAN + BB*EE)
#define OFF_HU   (OFF_C + BB*DD)
#define OFF_ATT  (OFF_HU + BB*AD)              /* reserved (ctx now fused into energy) */
#define OFF_GACC (OFF_ATT + BB*256)
#define OFF_HB   (OFF_GACC + BB*G4)            /* bf16 hb[64][512] */
#define OFF_XFB  (OFF_HB + BB*DD/2)            /* bf16 xfb[64][3072] */
#define OFF_WB   (OFF_XFB + BB*KX/2)           /* bf16 Wb[2048][3072] */
#define OFF_FCWB (OFF_WB + (size_t)G4*KX/2)    /* bf16 fcWb[10048][512] */
#define OFF_UAB  (OFF_FCWB + (size_t)VPAD*DD/2)/* bf16 Uab[512][512] */
#define OFF_WAB  (OFF_UAB + (size_t)AD*DD/2)   /* bf16 Wab[512][2048] */
#define OFF_WAEB (OFF_WAB + (size_t)AD*EE/2)   /* bf16 Waeb[12544][512] */
#define OFF_EBF  (OFF_WAEB + (size_t)BB*LL*AD/2) /* bf16 ebf[64][196][2048] */
// setup-only scratch overlaid on Waeb region (dead until k_waenc2 runs):
#define OFF_MEANB OFF_WAEB                       /* bf16 meanb[64][2048] = 65536 floats */
#define OFF_IHB  (OFF_WAEB + 65536)              /* bf16 ihb[512][2048] = 524288 floats */
#define OFF_ICB  (OFF_WAEB + 65536 + 524288)     /* bf16 icb[512][2048] */

typedef unsigned short u16;
typedef __attribute__((ext_vector_type(8))) short bf16x8;
typedef __attribute__((ext_vector_type(4))) float f32x4;
#define MFMA16(a,b,c) __builtin_amdgcn_mfma_f32_16x16x32_bf16(a,b,c,0,0,0)

__device__ inline u16 f2bf(float x){
    unsigned u = __float_as_uint(x);
    unsigned r = (u + 0x7FFFu + ((u >> 16) & 1u)) >> 16;
    return (u16)r;
}
__device__ inline float bf2f(u16 x){ return __uint_as_float(((unsigned)x) << 16); }
__device__ inline float sigm(float x){ return 1.0f/(1.0f + __expf(-x)); }
__device__ inline float ftanh(float x){ return 2.0f/(1.0f + __expf(-2.0f*x)) - 1.0f; }

__device__ inline void gload16(const u16* g, u16* l){
    __builtin_amdgcn_global_load_lds((const __attribute__((address_space(1))) void*)g,
                                     (__attribute__((address_space(3))) void*)l, 16, 0, 0);
}

// ---------------- sort (stable, descending length) ----------------
__global__ void k_sort(const int* __restrict__ lengths, const int* __restrict__ captions,
                       float* __restrict__ out, int* __restrict__ sidx, int* __restrict__ dl){
    __shared__ int len_s[BB];
    __shared__ int pos_s[BB];
    int i = threadIdx.x;
    len_s[i] = lengths[i];
    __syncthreads();
    int li = len_s[i];
    int rank = 0;
    for (int j = 0; j < BB; j++){
        int lj = len_s[j];
        rank += (lj > li) || (lj == li && j < i);
    }
    pos_s[rank] = i;
    __syncthreads();
    int src = pos_s[i];
    sidx[i] = src;
    int d = len_s[src] - 1;
    dl[i] = d;
    out[OUT_SIDX + i] = (float)src;
    out[OUT_DL + i]   = (float)d;
    for (int t = 0; t < TTOK; t++)
        out[OUT_CAPS + i*TTOK + t] = (float)captions[src*TTOK + t];
}

// ---------------- gacc bias seed + mean zero ----------------
__global__ void k_ginit(const float* __restrict__ b_ih, const float* __restrict__ b_hh,
                        float* __restrict__ gacc, float* __restrict__ mean){
    int gid = blockIdx.x*256 + threadIdx.x;
    if (gid < BB*G4){
        int j = gid & (G4-1);
        gacc[gid] = b_ih[j] + b_hh[j];
    } else {
        mean[gid - BB*G4] = 0.f;
    }
}

// ---------------- mean partial (atomic over l-halves) + bf16 copy of sorted enc ----------------
__global__ void k_meanbf(const float* __restrict__ enc, const int* __restrict__ sidx,
                         float* __restrict__ mean, u16* __restrict__ ebf){
    int b = blockIdx.y;
    int e = (blockIdx.x*256 + threadIdx.x)*4;
    int l0 = blockIdx.z*98, l1 = l0 + 98;
    int src = sidx[b];
    const float* p = enc + (size_t)src*LL*EE + e;
    u16* o = ebf + (size_t)b*LL*EE + e;
    float sx = 0.f, sy = 0.f, sz = 0.f, sw = 0.f;
    for (int l = l0; l < l1; l++){
        float4 v = *(const float4*)(p + (size_t)l*EE);
        sx += v.x; sy += v.y; sz += v.z; sw += v.w;
        unsigned lo = (unsigned)f2bf(v.x) | ((unsigned)f2bf(v.y) << 16);
        unsigned hi = (unsigned)f2bf(v.z) | ((unsigned)f2bf(v.w) << 16);
        uint2 pk; pk.x = lo; pk.y = hi;
        *(uint2*)(o + (size_t)l*EE) = pk;
    }
    atomicAdd(&mean[b*EE + e + 0], sx);
    atomicAdd(&mean[b*EE + e + 1], sy);
    atomicAdd(&mean[b*EE + e + 2], sz);
    atomicAdd(&mean[b*EE + e + 3], sw);
}

// ---------------- meanb = bf16(mean/196) ----------------
__global__ void k_meanb(const float* __restrict__ mean, u16* __restrict__ meanb){
    int i = (blockIdx.x*256 + threadIdx.x)*8;
    float4 a = *(const float4*)(mean + i);
    float4 b = *(const float4*)(mean + i + 4);
    const float s = 1.0f/196.0f;
    uint4 pk;
    pk.x = (unsigned)f2bf(a.x*s) | ((unsigned)f2bf(a.y*s) << 16);
    pk.y = (unsigned)f2bf(a.z*s) | ((unsigned)f2bf(a.w*s) << 16);
    pk.z = (unsigned)f2bf(b.x*s) | ((unsigned)f2bf(b.y*s) << 16);
    pk.w = (unsigned)f2bf(b.z*s) | ((unsigned)f2bf(b.w*s) << 16);
    *(uint4*)(meanb + i) = pk;
}

// ---------------- Wb[n][k] bf16 from W_ih|W_hh (already n-major) ----------------
__global__ void k_wb(const float* __restrict__ W_ih, const float* __restrict__ W_hh,
                     u16* __restrict__ Wb){
    int n = blockIdx.y;
    int k = blockIdx.x*256 + threadIdx.x;
    float v = (k < 2560) ? W_ih[(size_t)n*2560 + k] : W_hh[(size_t)n*512 + (k - 2560)];
    Wb[(size_t)n*KX + k] = f2bf(v);
}

// ---------------- generic transpose: in[K][N] f32 -> out[Nout][K] bf16 (zero-pad) ----------------
__global__ void k_tr(const float* __restrict__ in, u16* __restrict__ out, int K, int N){
    __shared__ float tile[32][33];
    int k0 = blockIdx.x*32, n0 = blockIdx.y*32;
    int tx = threadIdx.x, ty = threadIdx.y;
    for (int r = ty; r < 32; r += 8){
        int k = k0 + r, n = n0 + tx;
        tile[r][tx] = (n < N) ? in[(size_t)k*N + n] : 0.f;
    }
    __syncthreads();
    for (int r = ty; r < 32; r += 8){
        int n = n0 + r, k = k0 + tx;
        out[(size_t)n*K + k] = f2bf(tile[tx][r]);
    }
}

// ---------------- h0/c0 via MFMA: tanh(meanb @ ihb/icb^T + bias) ----------------
__global__ void k_h0c0m(const u16* __restrict__ ihb, const u16* __restrict__ icb,
                        const u16* __restrict__ meanb, const float* __restrict__ ih_b,
                        const float* __restrict__ ic_b, u16* __restrict__ hb,
                        float* __restrict__ c, u16* __restrict__ xfb){
    int tid = threadIdx.x, lane = tid & 63, w = tid >> 6;
    int lane15 = lane & 15, quad = lane >> 4;
    int z = blockIdx.y;
    const u16* Wm = z ? icb : ihb;
    const float* bias = z ? ic_b : ih_b;
    int n0 = blockIdx.x*64 + w*16;
    const u16* bp = Wm + (size_t)(n0 + lane15)*EE + quad*8;
    const u16* ap = meanb + (size_t)lane15*EE + quad*8;
    f32x4 zz = {0.f,0.f,0.f,0.f};
    f32x4 acc[4] = {zz,zz,zz,zz};
    #pragma unroll 4
    for (int kc = 0; kc < 64; kc++){
        bf16x8 bv = *(const bf16x8*)(bp + kc*32);
        bf16x8 a0 = *(const bf16x8*)(ap + kc*32);
        bf16x8 a1 = *(const bf16x8*)(ap + 16*EE + kc*32);
        bf16x8 a2 = *(const bf16x8*)(ap + 32*EE + kc*32);
        bf16x8 a3 = *(const bf16x8*)(ap + 48*EE + kc*32);
        acc[0] = MFMA16(a0, bv, acc[0]);
        acc[1] = MFMA16(a1, bv, acc[1]);
        acc[2] = MFMA16(a2, bv, acc[2]);
        acc[3] = MFMA16(a3, bv, acc[3]);
    }
    int j = n0 + lane15;
    float bj = bias[j];
    #pragma unroll
    for (int mt = 0; mt < 4; mt++)
        #pragma unroll
        for (int r = 0; r < 4; r++){
            int m = mt*16 + quad*4 + r;
            float v = tanhf(acc[mt][r] + bj);
            if (z == 0){
                u16 hv = f2bf(v);
                hb[m*DD + j] = hv;
                xfb[(size_t)m*KX + 2560 + j] = hv;
            } else {
                c[m*DD + j] = v;
            }
        }
}

// ---------------- Waeb = ebf @ Wab^T -- m97-style 128x128 LDS double-buffered GEMM ----------------
// A = ebf[12544][2048] bf16, B = Wab[512][2048] bf16 (N-major, K contiguous), C = Waeb[12544][512] bf16
#define BKK 64
__global__ __launch_bounds__(256) void k_waenc2(const u16* __restrict__ ebf,
                                                const u16* __restrict__ Wab,
                                                u16* __restrict__ Waeb){
    __shared__ __align__(16) u16 As[2][128*BKK];
    __shared__ __align__(16) u16 Bs[2][128*BKK];
    int tid = threadIdx.x, lane = tid & 63, w = tid >> 6;
    int lane15 = lane & 15, quad = lane >> 4;
    int m0 = blockIdx.x * 128;
    int n0 = blockIdx.y * 128;

    // staging: each global_load_lds issue covers 32 rows x 64 k (256 thr x 16B)
    // LDS is linear; global SOURCE column is pre-XOR-swizzled (rule #21 both-sides):
    //   lds[r][c] holds global[r][ c ^ 8*(r&7) ]   (c in u16 elements, 8-granular)
    int srow = w*8 + (lane >> 3);                 // row within 32-row chunk (row&7 = lane>>3)
    int scol = 8 * ((lane & 7) ^ (lane >> 3));    // swizzled source column
    const u16* ag = ebf + (size_t)(m0 + srow)*EE + scol;
    const u16* bg = Wab + (size_t)(n0 + srow)*EE + scol;

    f32x4 zz = {0.f,0.f,0.f,0.f};
    f32x4 acc[4][4];
    #pragma unroll
    for (int mt = 0; mt < 4; mt++)
        #pragma unroll
        for (int nt = 0; nt < 4; nt++) acc[mt][nt] = zz;

    int ar  = (w >> 1) * 64;    // wave row-tile base
    int brr = (w & 1) * 64;     // wave col-tile base
    int rx  = (lane15 & 7) << 3; // read-side swizzle (row&7 of fragment rows)

    // prologue: stage K-tile 0 into buffer 0
    {
        u16* la = &As[0][w*512 + lane*8];
        u16* lb = &Bs[0][w*512 + lane*8];
        #pragma unroll
        for (int i = 0; i < 4; i++){
            gload16(ag + (size_t)(i*32)*EE, la + i*2048);
            gload16(bg + (size_t)(i*32)*EE, lb + i*2048);
        }
    }
    __syncthreads();

    int cur = 0;
    for (int kt = 0; kt < 32; kt++){
        if (kt < 31){
            u16* la = &As[cur^1][w*512 + lane*8];
            u16* lb = &Bs[cur^1][w*512 + lane*8];
            const u16* a = ag + (size_t)(kt+1)*BKK;
            const u16* b = bg + (size_t)(kt+1)*BKK;
            #pragma unroll
            for (int i = 0; i < 4; i++){
                gload16(a + (size_t)(i*32)*EE, la + i*2048);
                gload16(b + (size_t)(i*32)*EE, lb + i*2048);
            }
        }
        bf16x8 af[4][2], bfr[4][2];
        #pragma unroll
        for (int mt = 0; mt < 4; mt++)
            #pragma unroll
            for (int ks = 0; ks < 2; ks++){
                af[mt][ks]  = *(const bf16x8*)&As[cur][(ar  + mt*16 + lane15)*BKK + ((ks*32 + quad*8) ^ rx)];
                bfr[mt][ks] = *(const bf16x8*)&Bs[cur][(brr + mt*16 + lane15)*BKK + ((ks*32 + quad*8) ^ rx)];
            }
        #pragma unroll
        for (int ks = 0; ks < 2; ks++)
            #pragma unroll
            for (int mt = 0; mt < 4; mt++)
                #pragma unroll
                for (int nt = 0; nt < 4; nt++)
                    acc[mt][nt] = MFMA16(af[mt][ks], bfr[nt][ks], acc[mt][nt]);
        __syncthreads();   // drains vmcnt (staged buffer ready) + lgkm (reads done)
        cur ^= 1;
    }

    #pragma unroll
    for (int mt = 0; mt < 4; mt++)
        #pragma unroll
        for (int nt = 0; nt < 4; nt++)
            #pragma unroll
            for (int r = 0; r < 4; r++){
                int row = m0 + ar + mt*16 + quad*4 + r;
                Waeb[(size_t)row*AD + n0 + brr + nt*16 + lane15] = f2bf(acc[mt][nt][r]);
            }
}

// ---------------- per-step: emb gather + energy + softmax + beta + context (fused) ----------------
__global__ __launch_bounds__(512) void k_energy(const u16* __restrict__ Waeb,
                       const float* __restrict__ hU, const u16* __restrict__ hb,
                       const float* __restrict__ w_att, const float* __restrict__ fb_W,
                       const float* __restrict__ fb_b, const float* __restrict__ emb_table,
                       const int* __restrict__ captions, const int* __restrict__ sidx,
                       const int* __restrict__ dl, const u16* __restrict__ ebf,
                       u16* __restrict__ xfb, float* __restrict__ out, int t){
    __shared__ float red[512];
    __shared__ float en_s[200];
    __shared__ float alpha_s[LL];
    __shared__ float sbeta;
    int b = blockIdx.x, tid = threadIdx.x;
    int lane = tid & 63, w = tid >> 6;

    int cap = captions[sidx[b]*TTOK + t];
    xfb[(size_t)b*KX + tid] = f2bf(emb_table[(size_t)cap*EM + tid]);

    const float* hub = hU + (size_t)b*AD;
    float hw[8], ww[8];
    #pragma unroll
    for (int ii = 0; ii < 8; ii++){
        hw[ii] = hub[ii*64 + lane];
        ww[ii] = w_att[ii*64 + lane];
    }
    for (int l = w; l < LL; l += 8){
        const u16* wa = Waeb + ((size_t)b*LL + l)*AD;
        float acc = 0.f;
        #pragma unroll
        for (int ii = 0; ii < 8; ii++)
            acc += ftanh(bf2f(wa[ii*64 + lane]) + hw[ii]) * ww[ii];
        #pragma unroll
        for (int off = 32; off; off >>= 1) acc += __shfl_xor(acc, off, 64);
        if (lane == 0) en_s[l] = acc;
    }
    __syncthreads();

    red[tid] = (tid < LL) ? en_s[tid] : -3.0e38f;
    __syncthreads();
    for (int s = 256; s > 0; s >>= 1){ if (tid < s) red[tid] = fmaxf(red[tid], red[tid+s]); __syncthreads(); }
    float mx = red[0]; __syncthreads();
    float p = (tid < LL) ? __expf(en_s[tid] - mx) : 0.f;
    red[tid] = p; __syncthreads();
    for (int s = 256; s > 0; s >>= 1){ if (tid < s) red[tid] += red[tid+s]; __syncthreads(); }
    float ssum = red[0]; __syncthreads();
    float alpha = p / ssum;
    if (tid < LL){
        alpha_s[tid] = alpha;
        out[OUT_ALPH + ((size_t)b*MT + t)*LL + tid] = (t < dl[b]) ? alpha : 0.f;
    }

    red[tid] = bf2f(hb[b*DD + tid]) * fb_W[tid];
    __syncthreads();
    for (int s = 256; s > 0; s >>= 1){ if (tid < s) red[tid] += red[tid+s]; __syncthreads(); }
    if (tid == 0) sbeta = sigm(red[0] + fb_b[0]);
    __syncthreads();

    // ---- context: each thread owns 4 e-dims, loop over all 196 l ----
    float beta = sbeta;
    float a0 = 0.f, a1 = 0.f, a2 = 0.f, a3 = 0.f;
    const u16* pe = ebf + (size_t)b*LL*EE + tid*4;
    #pragma unroll 4
    for (int l = 0; l < LL; l++){
        uint2 u = *(const uint2*)(pe + (size_t)l*EE);
        float al = alpha_s[l];
        a0 += al * __uint_as_float(u.x << 16);
        a1 += al * __uint_as_float(u.x & 0xFFFF0000u);
        a2 += al * __uint_as_float(u.y << 16);
        a3 += al * __uint_as_float(u.y & 0xFFFF0000u);
    }
    uint2 pk;
    pk.x = (unsigned)f2bf(beta*a0) | ((unsigned)f2bf(beta*a1) << 16);
    pk.y = (unsigned)f2bf(beta*a2) | ((unsigned)f2bf(beta*a3) << 16);
    *(uint2*)(xfb + (size_t)b*KX + EM + tid*4) = pk;
}

// ---------------- per-step: gates MFMA (K-split x4, atomic into pre-seeded gacc) ----------------
__global__ void k_gates(const u16* __restrict__ Wb, const u16* __restrict__ xfb,
                        float* __restrict__ gacc){
    int tid = threadIdx.x, lane = tid & 63, w = tid >> 6;
    int lane15 = lane & 15, quad = lane >> 4;
    int n0 = blockIdx.x*64 + w*16;
    int kbase = blockIdx.y*768;
    const u16* bp = Wb + (size_t)(n0 + lane15)*KX + kbase + quad*8;
    const u16* ap = xfb + (size_t)lane15*KX + kbase + quad*8;
    f32x4 z = {0.f,0.f,0.f,0.f};
    f32x4 acc[4] = {z,z,z,z};
    #pragma unroll 4
    for (int kc = 0; kc < 24; kc++){
        bf16x8 bv = *(const bf16x8*)(bp + kc*32);
        bf16x8 a0 = *(const bf16x8*)(ap + kc*32);
        bf16x8 a1 = *(const bf16x8*)(ap + 16*KX + kc*32);
        bf16x8 a2 = *(const bf16x8*)(ap + 32*KX + kc*32);
        bf16x8 a3 = *(const bf16x8*)(ap + 48*KX + kc*32);
        acc[0] = MFMA16(a0, bv, acc[0]);
        acc[1] = MFMA16(a1, bv, acc[1]);
        acc[2] = MFMA16(a2, bv, acc[2]);
        acc[3] = MFMA16(a3, bv, acc[3]);
    }
    #pragma unroll
    for (int mt = 0; mt < 4; mt++)
        #pragma unroll
        for (int r = 0; r < 4; r++){
            int m = mt*16 + quad*4 + r;
            atomicAdd(&gacc[(size_t)m*G4 + n0 + lane15], acc[mt][r]);
        }
}

// ---------------- per-step: LSTM state update (+ reseed gacc with biases) ----------------
__global__ void k_update(float* __restrict__ gacc, const float* __restrict__ b_ih,
                         const float* __restrict__ b_hh, const int* __restrict__ dl,
                         u16* __restrict__ hb, float* __restrict__ c,
                         u16* __restrict__ xfb, int t){
    int gid = blockIdx.x*256 + threadIdx.x;
    int b = gid >> 9, d = gid & 511;
    size_t base = (size_t)b*G4 + d;
    float gi = gacc[base];
    float gf = gacc[base + 512];
    float gg = gacc[base + 1024];
    float go = gacc[base + 1536];
    float ig = sigm(gi), fg = sigm(gf), g = ftanh(gg), o = sigm(go);
    float cold = c[gid];
    float cn = fg*cold + ig*g;
    float hn = o*ftanh(cn);
    if (t < dl[b]){
        c[gid] = cn;
        u16 hv = f2bf(hn);
        hb[gid] = hv;
        xfb[(size_t)b*KX + 2560 + d] = hv;
    }
    gacc[base]        = b_ih[d]        + b_hh[d];
    gacc[base + 512]  = b_ih[d + 512]  + b_hh[d + 512];
    gacc[base + 1024] = b_ih[d + 1024] + b_hh[d + 1024];
    gacc[base + 1536] = b_ih[d + 1536] + b_hh[d + 1536];
}

// ---------------- per-step: fc prediction + next-step hU (MFMA) ----------------
__global__ void k_pred(const u16* __restrict__ fcWb, const float* __restrict__ fc_b,
                       const u16* __restrict__ Uab, const u16* __restrict__ hb,
                       const int* __restrict__ dl, float* __restrict__ out,
                       float* __restrict__ hU, int t, int hu_only){
    int tid = threadIdx.x, lane = tid & 63, w = tid >> 6;
    int lane15 = lane & 15, quad = lane >> 4;
    int bid = blockIdx.x;
    bool pred; int jc;
    if (hu_only){ pred = false; jc = bid; }
    else if (bid < 157){ pred = true; jc = bid; }
    else { pred = false; jc = bid - 157; }
    const u16* W = pred ? fcWb : Uab;
    int n0 = jc*64 + w*16;
    const u16* bp = W + (size_t)(n0 + lane15)*AD + quad*8;
    const u16* ap = hb + (size_t)lane15*AD + quad*8;
    f32x4 z = {0.f,0.f,0.f,0.f};
    f32x4 acc[4] = {z,z,z,z};
    #pragma unroll 4
    for (int kc = 0; kc < 16; kc++){
        bf16x8 bv = *(const bf16x8*)(bp + kc*32);
        bf16x8 a0 = *(const bf16x8*)(ap + kc*32);
        bf16x8 a1 = *(const bf16x8*)(ap + 16*AD + kc*32);
        bf16x8 a2 = *(const bf16x8*)(ap + 32*AD + kc*32);
        bf16x8 a3 = *(const bf16x8*)(ap + 48*AD + kc*32);
        acc[0] = MFMA16(a0, bv, acc[0]);
        acc[1] = MFMA16(a1, bv, acc[1]);
        acc[2] = MFMA16(a2, bv, acc[2]);
        acc[3] = MFMA16(a3, bv, acc[3]);
    }
    if (pred){
        int j = n0 + lane15;
        if (j < VV){
            float bias = fc_b[j];
            #pragma unroll
            for (int mt = 0; mt < 4; mt++)
                #pragma unroll
                for (int r = 0; r < 4; r++){
                    int b = mt*16 + quad*4 + r;
                    bool mk = t < dl[b];
                    out[OUT_PRED + ((size_t)b*MT + t)*VV + j] = mk ? acc[mt][r] + bias : 0.f;
                }
        }
    } else {
        int n = n0 + lane15;
        #pragma unroll
        for (int mt = 0; mt < 4; mt++)
            #pragma unroll
            for (int r = 0; r < 4; r++){
                int b = mt*16 + quad*4 + r;
                hU[(size_t)b*AD + n] = acc[mt][r];
            }
    }
}

extern "C" void kernel_launch(void* const* d_in, const int* in_sizes, int n_in,
                              void* d_out, int out_size, void* d_ws, size_t ws_size,
                              hipStream_t stream) {
    const float* enc       = (const float*)d_in[0];
    const int*   captions  = (const int*)d_in[1];
    const int*   lengths   = (const int*)d_in[2];
    const float* emb_table = (const float*)d_in[3];
    const float* W_a       = (const float*)d_in[4];
    const float* U_a       = (const float*)d_in[5];
    const float* w_att     = (const float*)d_in[6];
    const float* fb_W      = (const float*)d_in[7];
    const float* fb_b      = (const float*)d_in[8];
    const float* W_ih      = (const float*)d_in[9];
    const float* W_hh      = (const float*)d_in[10];
    const float* b_ih      = (const float*)d_in[11];
    const float* b_hh      = (const float*)d_in[12];
    const float* fc_W      = (const float*)d_in[13];
    const float* fc_b      = (const float*)d_in[14];
    const float* ih_W      = (const float*)d_in[15];
    const float* ih_b      = (const float*)d_in[16];
    const float* ic_W      = (const float*)d_in[17];
    const float* ic_b      = (const float*)d_in[18];

    float* out = (float*)d_out;
    float* ws  = (float*)d_ws;
    int* sidx = (int*)(ws + OFF_SIDX);
    int* dl   = (int*)(ws + OFF_DL);
    float* mean = ws + OFF_MEAN;
    float* c    = ws + OFF_C;
    float* hU   = ws + OFF_HU;
    float* gacc = ws + OFF_GACC;
    u16* hb   = (u16*)(ws + OFF_HB);
    u16* xfb  = (u16*)(ws + OFF_XFB);
    u16* Wb   = (u16*)(ws + OFF_WB);
    u16* fcWb = (u16*)(ws + OFF_FCWB);
    u16* Uab  = (u16*)(ws + OFF_UAB);
    u16* Wab  = (u16*)(ws + OFF_WAB);
    u16* Waeb = (u16*)(ws + OFF_WAEB);
    u16* ebf  = (u16*)(ws + OFF_EBF);
    u16* meanb = (u16*)(ws + OFF_MEANB);
    u16* ihb  = (u16*)(ws + OFF_IHB);
    u16* icb  = (u16*)(ws + OFF_ICB);

    k_sort<<<1, 64, 0, stream>>>(lengths, captions, out, sidx, dl);
    k_ginit<<<1024, 256, 0, stream>>>(b_ih, b_hh, gacc, mean);
    k_meanbf<<<dim3(2, BB, 2), 256, 0, stream>>>(enc, sidx, mean, ebf);
    k_meanb<<<64, 256, 0, stream>>>(mean, meanb);
    k_tr<<<dim3(64, 16), dim3(32, 8), 0, stream>>>(ih_W, ihb, 2048, 512);
    k_tr<<<dim3(64, 16), dim3(32, 8), 0, stream>>>(ic_W, icb, 2048, 512);
    k_h0c0m<<<dim3(8, 2), 256, 0, stream>>>(ihb, icb, meanb, ih_b, ic_b, hb, c, xfb);
    k_wb<<<dim3(12, G4), 256, 0, stream>>>(W_ih, W_hh, Wb);
    k_tr<<<dim3(16, 314), dim3(32, 8), 0, stream>>>(fc_W, fcWb, 512, VV);
    k_tr<<<dim3(16, 16),  dim3(32, 8), 0, stream>>>(U_a, Uab, 512, 512);
    k_tr<<<dim3(64, 16),  dim3(32, 8), 0, stream>>>(W_a, Wab, 2048, 512);
    k_waenc2<<<dim3(98, 4), 256, 0, stream>>>(ebf, Wab, Waeb);
    k_pred<<<8, 256, 0, stream>>>(fcWb, fc_b, Uab, hb, dl, out, hU, 0, 1);

    for (int t = 0; t < MT; t++){
        k_energy<<<BB, 512, 0, stream>>>(Waeb, hU, hb, w_att, fb_W, fb_b,
                                         emb_table, captions, sidx, dl, ebf, xfb, out, t);
        k_gates<<<dim3(32, 4), 256, 0, stream>>>(Wb, xfb, gacc);
        k_update<<<128, 256, 0, stream>>>(gacc, b_ih, b_hh, dl, hb, c, xfb, t);
        k_pred<<<165, 256, 0, stream>>>(fcWb, fc_b, Uab, hb, dl, out, hU, t, 0);
    }
}

// Round 3
// 2228.578 us; speedup vs baseline: 1.4324x; 1.4324x over previous
//
#include <hip/hip_runtime.h>
#include <cstdint>
#include <cstddef>

// ---------------- problem constants ----------------
#define BB 64
#define LL 196
#define EE 2048
#define AD 512
#define DD 512
#define EM 512
#define VV 10000
#define TTOK 32
#define MT 31
#define KX 3072   /* xfull = [emb 512 | ctx 2048 | h 512] */
#define G4 2048   /* 4*DD */
#define VPAD 10048 /* 157*64 */

// ---------------- output offsets (floats) ----------------
#define OUT_PRED 0
#define OUT_CAPS (BB*MT*VV)
#define OUT_DL   (OUT_CAPS + BB*TTOK)
#define OUT_ALPH (OUT_DL + BB)
#define OUT_SIDX (OUT_ALPH + BB*MT*LL)

// ---------------- workspace offsets (floats, all 64-aligned) ----------------
#define OFF_SIDX 0
#define OFF_DL   64
#define OFF_MEAN 128
#define OFF_C    (OFF_MEAN + BB*EE)
#define OFF_HU   (OFF_C + BB*DD)
#define OFF_ATT  (OFF_HU + BB*AD)              /* en[64][256] raw energies */
#define OFF_GACC (OFF_ATT + BB*256)            /* gacc[64][2048]; first 65536 floats double as h0c0 scratch */
#define OFF_HB   (OFF_GACC + BB*G4)            /* bf16 hb[64][512] */
#define OFF_XFB  (OFF_HB + BB*DD/2)            /* bf16 xfb[64][3072] */
#define OFF_WB   (OFF_XFB + BB*KX/2)           /* bf16 Wb[2048][3072] */
#define OFF_FCWB (OFF_WB + (size_t)G4*KX/2)    /* bf16 fcWb[10048][512] */
#define OFF_UAB  (OFF_FCWB + (size_t)VPAD*DD/2)/* bf16 Uab[512][512] */
#define OFF_WAB  (OFF_UAB + (size_t)AD*DD/2)   /* bf16 Wab[512][2048] */
#define OFF_WAEB (OFF_WAB + (size_t)AD*EE/2)   /* bf16 Waeb[12544][512] */
#define OFF_EBF  (OFF_WAEB + (size_t)BB*LL*AD/2) /* bf16 ebf[64][196][2048] */
// setup-only scratch overlaid on Waeb region (dead until k_waenc2 runs):
#define OFF_MEANB OFF_WAEB                       /* bf16 meanb[64][2048] = 65536 floats */
#define OFF_IHB  (OFF_WAEB + 65536)              /* bf16 ihb[512][2048] = 524288 floats */
#define OFF_ICB  (OFF_WAEB + 65536 + 524288)     /* bf16 icb[512][2048] */

typedef unsigned short u16;
typedef __attribute__((ext_vector_type(8))) short bf16x8;
typedef __attribute__((ext_vector_type(4))) float f32x4;
#define MFMA16(a,b,c) __builtin_amdgcn_mfma_f32_16x16x32_bf16(a,b,c,0,0,0)

__device__ inline u16 f2bf(float x){
    unsigned u = __float_as_uint(x);
    unsigned r = (u + 0x7FFFu + ((u >> 16) & 1u)) >> 16;
    return (u16)r;
}
__device__ inline float bf2f(u16 x){ return __uint_as_float(((unsigned)x) << 16); }
__device__ inline float sigm(float x){ return 1.0f/(1.0f + __expf(-x)); }
__device__ inline float ftanh(float x){ return 2.0f/(1.0f + __expf(-2.0f*x)) - 1.0f; }

__device__ inline void gload16(const u16* g, u16* l){
    __builtin_amdgcn_global_load_lds((const __attribute__((address_space(1))) void*)g,
                                     (__attribute__((address_space(3))) void*)l, 16, 0, 0);
}

// ---------------- sort (stable, descending length) ----------------
__global__ void k_sort(const int* __restrict__ lengths, const int* __restrict__ captions,
                       float* __restrict__ out, int* __restrict__ sidx, int* __restrict__ dl){
    __shared__ int len_s[BB];
    __shared__ int pos_s[BB];
    int i = threadIdx.x;
    len_s[i] = lengths[i];
    __syncthreads();
    int li = len_s[i];
    int rank = 0;
    for (int j = 0; j < BB; j++){
        int lj = len_s[j];
        rank += (lj > li) || (lj == li && j < i);
    }
    pos_s[rank] = i;
    __syncthreads();
    int src = pos_s[i];
    sidx[i] = src;
    int d = len_s[src] - 1;
    dl[i] = d;
    out[OUT_SIDX + i] = (float)src;
    out[OUT_DL + i]   = (float)d;
    for (int t = 0; t < TTOK; t++)
        out[OUT_CAPS + i*TTOK + t] = (float)captions[src*TTOK + t];
}

// ---------------- zero h0c0 scratch (first 65536 of gacc) + zero mean ----------------
__global__ void k_ginit(float* __restrict__ gacc, float* __restrict__ mean){
    int gid = blockIdx.x*256 + threadIdx.x;
    if (gid < 65536) gacc[gid] = 0.f;
    else mean[gid - 65536] = 0.f;
}

// ---------------- mean partial (atomic over l-halves) + bf16 copy of sorted enc ----------------
__global__ void k_meanbf(const float* __restrict__ enc, const int* __restrict__ sidx,
                         float* __restrict__ mean, u16* __restrict__ ebf){
    int b = blockIdx.y;
    int e = (blockIdx.x*256 + threadIdx.x)*4;
    int l0 = blockIdx.z*98, l1 = l0 + 98;
    int src = sidx[b];
    const float* p = enc + (size_t)src*LL*EE + e;
    u16* o = ebf + (size_t)b*LL*EE + e;
    float sx = 0.f, sy = 0.f, sz = 0.f, sw = 0.f;
    for (int l = l0; l < l1; l++){
        float4 v = *(const float4*)(p + (size_t)l*EE);
        sx += v.x; sy += v.y; sz += v.z; sw += v.w;
        unsigned lo = (unsigned)f2bf(v.x) | ((unsigned)f2bf(v.y) << 16);
        unsigned hi = (unsigned)f2bf(v.z) | ((unsigned)f2bf(v.w) << 16);
        uint2 pk; pk.x = lo; pk.y = hi;
        *(uint2*)(o + (size_t)l*EE) = pk;
    }
    atomicAdd(&mean[b*EE + e + 0], sx);
    atomicAdd(&mean[b*EE + e + 1], sy);
    atomicAdd(&mean[b*EE + e + 2], sz);
    atomicAdd(&mean[b*EE + e + 3], sw);
}

// ---------------- meanb = bf16(mean/196) ----------------
__global__ void k_meanb(const float* __restrict__ mean, u16* __restrict__ meanb){
    int i = (blockIdx.x*256 + threadIdx.x)*8;
    float4 a = *(const float4*)(mean + i);
    float4 b = *(const float4*)(mean + i + 4);
    const float s = 1.0f/196.0f;
    uint4 pk;
    pk.x = (unsigned)f2bf(a.x*s) | ((unsigned)f2bf(a.y*s) << 16);
    pk.y = (unsigned)f2bf(a.z*s) | ((unsigned)f2bf(a.w*s) << 16);
    pk.z = (unsigned)f2bf(b.x*s) | ((unsigned)f2bf(b.y*s) << 16);
    pk.w = (unsigned)f2bf(b.z*s) | ((unsigned)f2bf(b.w*s) << 16);
    *(uint4*)(meanb + i) = pk;
}

// ---------------- Wb[n][k] bf16 from W_ih|W_hh (already n-major) ----------------
__global__ void k_wb(const float* __restrict__ W_ih, const float* __restrict__ W_hh,
                     u16* __restrict__ Wb){
    int n = blockIdx.y;
    int k = blockIdx.x*256 + threadIdx.x;
    float v = (k < 2560) ? W_ih[(size_t)n*2560 + k] : W_hh[(size_t)n*512 + (k - 2560)];
    Wb[(size_t)n*KX + k] = f2bf(v);
}

// ---------------- generic transpose: in[K][N] f32 -> out[Nout][K] bf16 (zero-pad) ----------------
__global__ void k_tr(const float* __restrict__ in, u16* __restrict__ out, int K, int N){
    __shared__ float tile[32][33];
    int k0 = blockIdx.x*32, n0 = blockIdx.y*32;
    int tx = threadIdx.x, ty = threadIdx.y;
    for (int r = ty; r < 32; r += 8){
        int k = k0 + r, n = n0 + tx;
        tile[r][tx] = (n < N) ? in[(size_t)k*N + n] : 0.f;
    }
    __syncthreads();
    for (int r = ty; r < 32; r += 8){
        int n = n0 + r, k = k0 + tx;
        out[(size_t)n*K + k] = f2bf(tile[tx][r]);
    }
}

// ---------------- h0/c0 partials: K-split x4, atomic into hc scratch (= gacc[0..65536]) ----------------
// hc[z][m][j] at gacc[z*32768 + m*512 + j]
__global__ void k_h0c0s(const u16* __restrict__ ihb, const u16* __restrict__ icb,
                        const u16* __restrict__ meanb, float* __restrict__ hc){
    int tid = threadIdx.x, lane = tid & 63, w = tid >> 6;
    int lane15 = lane & 15, quad = lane >> 4;
    int z = blockIdx.y;
    int ks = blockIdx.z;          // K chunk of 512
    const u16* Wm = z ? icb : ihb;
    int n0 = blockIdx.x*64 + w*16;
    const u16* bp = Wm + (size_t)(n0 + lane15)*EE + ks*512 + quad*8;
    const u16* ap = meanb + (size_t)lane15*EE + ks*512 + quad*8;
    f32x4 zz = {0.f,0.f,0.f,0.f};
    f32x4 acc[4] = {zz,zz,zz,zz};
    #pragma unroll 4
    for (int kc = 0; kc < 16; kc++){
        bf16x8 bv = *(const bf16x8*)(bp + kc*32);
        bf16x8 a0 = *(const bf16x8*)(ap + kc*32);
        bf16x8 a1 = *(const bf16x8*)(ap + 16*EE + kc*32);
        bf16x8 a2 = *(const bf16x8*)(ap + 32*EE + kc*32);
        bf16x8 a3 = *(const bf16x8*)(ap + 48*EE + kc*32);
        acc[0] = MFMA16(a0, bv, acc[0]);
        acc[1] = MFMA16(a1, bv, acc[1]);
        acc[2] = MFMA16(a2, bv, acc[2]);
        acc[3] = MFMA16(a3, bv, acc[3]);
    }
    int j = n0 + lane15;
    #pragma unroll
    for (int mt = 0; mt < 4; mt++)
        #pragma unroll
        for (int r = 0; r < 4; r++){
            int m = mt*16 + quad*4 + r;
            atomicAdd(&hc[z*32768 + m*512 + j], acc[mt][r]);
        }
}

// ---------------- h0/c0 finisher: tanh(+bias) -> hb/c/xfb, then reseed gacc with biases ----------------
__global__ void k_h0c0f(float* __restrict__ gacc, const float* __restrict__ ih_b,
                        const float* __restrict__ ic_b, const float* __restrict__ b_ih,
                        const float* __restrict__ b_hh, u16* __restrict__ hb,
                        float* __restrict__ c, u16* __restrict__ xfb){
    int gid = blockIdx.x*256 + threadIdx.x;   // 0..131071
    if (gid < 65536){
        int z = gid >> 15;            // 0=h, 1=c
        int mj = gid & 32767;
        int m = mj >> 9, j = mj & 511;
        float v = tanhf(gacc[gid] + (z ? ic_b[j] : ih_b[j]));
        if (z == 0){
            u16 hv = f2bf(v);
            hb[m*DD + j] = hv;
            xfb[(size_t)m*KX + 2560 + j] = hv;
        } else {
            c[m*DD + j] = v;
        }
    }
    int jj = gid & (G4-1);
    gacc[gid] = b_ih[jj] + b_hh[jj];
}

// ---------------- Waeb = ebf @ Wab^T -- m97-style 128x128 LDS double-buffered GEMM ----------------
#define BKK 64
__global__ __launch_bounds__(256) void k_waenc2(const u16* __restrict__ ebf,
                                                const u16* __restrict__ Wab,
                                                u16* __restrict__ Waeb){
    __shared__ __align__(16) u16 As[2][128*BKK];
    __shared__ __align__(16) u16 Bs[2][128*BKK];
    int tid = threadIdx.x, lane = tid & 63, w = tid >> 6;
    int lane15 = lane & 15, quad = lane >> 4;
    int m0 = blockIdx.x * 128;
    int n0 = blockIdx.y * 128;

    int srow = w*8 + (lane >> 3);
    int scol = 8 * ((lane & 7) ^ (lane >> 3));
    const u16* ag = ebf + (size_t)(m0 + srow)*EE + scol;
    const u16* bg = Wab + (size_t)(n0 + srow)*EE + scol;

    f32x4 zz = {0.f,0.f,0.f,0.f};
    f32x4 acc[4][4];
    #pragma unroll
    for (int mt = 0; mt < 4; mt++)
        #pragma unroll
        for (int nt = 0; nt < 4; nt++) acc[mt][nt] = zz;

    int ar  = (w >> 1) * 64;
    int brr = (w & 1) * 64;
    int rx  = (lane15 & 7) << 3;

    {
        u16* la = &As[0][w*512 + lane*8];
        u16* lb = &Bs[0][w*512 + lane*8];
        #pragma unroll
        for (int i = 0; i < 4; i++){
            gload16(ag + (size_t)(i*32)*EE, la + i*2048);
            gload16(bg + (size_t)(i*32)*EE, lb + i*2048);
        }
    }
    __syncthreads();

    int cur = 0;
    for (int kt = 0; kt < 32; kt++){
        if (kt < 31){
            u16* la = &As[cur^1][w*512 + lane*8];
            u16* lb = &Bs[cur^1][w*512 + lane*8];
            const u16* a = ag + (size_t)(kt+1)*BKK;
            const u16* b = bg + (size_t)(kt+1)*BKK;
            #pragma unroll
            for (int i = 0; i < 4; i++){
                gload16(a + (size_t)(i*32)*EE, la + i*2048);
                gload16(b + (size_t)(i*32)*EE, lb + i*2048);
            }
        }
        bf16x8 af[4][2], bfr[4][2];
        #pragma unroll
        for (int mt = 0; mt < 4; mt++)
            #pragma unroll
            for (int ks = 0; ks < 2; ks++){
                af[mt][ks]  = *(const bf16x8*)&As[cur][(ar  + mt*16 + lane15)*BKK + ((ks*32 + quad*8) ^ rx)];
                bfr[mt][ks] = *(const bf16x8*)&Bs[cur][(brr + mt*16 + lane15)*BKK + ((ks*32 + quad*8) ^ rx)];
            }
        #pragma unroll
        for (int ks = 0; ks < 2; ks++)
            #pragma unroll
            for (int mt = 0; mt < 4; mt++)
                #pragma unroll
                for (int nt = 0; nt < 4; nt++)
                    acc[mt][nt] = MFMA16(af[mt][ks], bfr[nt][ks], acc[mt][nt]);
        __syncthreads();
        cur ^= 1;
    }

    #pragma unroll
    for (int mt = 0; mt < 4; mt++)
        #pragma unroll
        for (int nt = 0; nt < 4; nt++)
            #pragma unroll
            for (int r = 0; r < 4; r++){
                int row = m0 + ar + mt*16 + quad*4 + r;
                Waeb[(size_t)row*AD + n0 + brr + nt*16 + lane15] = f2bf(acc[mt][nt][r]);
            }
}

// ---------------- per-step: raw energies, wide (256 blocks = 64b x 4sub, 49 rows each) ----------------
__global__ __launch_bounds__(256) void k_energyA(const u16* __restrict__ Waeb,
                       const float* __restrict__ hU, const float* __restrict__ w_att,
                       float* __restrict__ en){
    int tid = threadIdx.x, lane = tid & 63, w = tid >> 6;
    int b = blockIdx.x >> 2, sub = blockIdx.x & 3;

    const float* hub = hU + (size_t)b*AD;
    float hw[8], ww[8];
    #pragma unroll
    for (int ii = 0; ii < 8; ii++){
        hw[ii] = hub[ii*64 + lane];
        ww[ii] = w_att[ii*64 + lane];
    }
    int l0 = sub*49;
    for (int l = l0 + w; l < l0 + 49; l += 4){
        const u16* wa = Waeb + ((size_t)b*LL + l)*AD;
        float acc = 0.f;
        #pragma unroll
        for (int ii = 0; ii < 8; ii++)
            acc += ftanh(bf2f(wa[ii*64 + lane]) + hw[ii]) * ww[ii];
        #pragma unroll
        for (int off = 32; off; off >>= 1) acc += __shfl_xor(acc, off, 64);
        if (lane == 0) en[b*256 + l] = acc;
    }
}

// ---------------- per-step: softmax + beta + emb + context (grid (4,64)) ----------------
__global__ __launch_bounds__(256) void k_ctx(const float* __restrict__ en,
                      const u16* __restrict__ ebf, const u16* __restrict__ hb,
                      const float* __restrict__ fb_W, const float* __restrict__ fb_b,
                      const float* __restrict__ emb_table, const int* __restrict__ captions,
                      const int* __restrict__ sidx, const int* __restrict__ dl,
                      u16* __restrict__ xfb, float* __restrict__ out, int t){
    __shared__ float red[256];
    __shared__ float alpha_s[LL];
    __shared__ float sbeta;
    int b = blockIdx.y, q = blockIdx.x, tid = threadIdx.x;

    float e = (tid < LL) ? en[b*256 + tid] : -3.0e38f;
    red[tid] = e; __syncthreads();
    for (int s = 128; s > 0; s >>= 1){ if (tid < s) red[tid] = fmaxf(red[tid], red[tid+s]); __syncthreads(); }
    float mx = red[0]; __syncthreads();
    float p = (tid < LL) ? __expf(e - mx) : 0.f;
    red[tid] = p; __syncthreads();
    for (int s = 128; s > 0; s >>= 1){ if (tid < s) red[tid] += red[tid+s]; __syncthreads(); }
    float ssum = red[0]; __syncthreads();
    float alpha = p / ssum;
    if (tid < LL){
        alpha_s[tid] = alpha;
        if (q == 0)
            out[OUT_ALPH + ((size_t)b*MT + t)*LL + tid] = (t < dl[b]) ? alpha : 0.f;
    }

    red[tid] = bf2f(hb[b*DD + tid]) * fb_W[tid]
             + bf2f(hb[b*DD + 256 + tid]) * fb_W[256 + tid];
    __syncthreads();
    for (int s = 128; s > 0; s >>= 1){ if (tid < s) red[tid] += red[tid+s]; __syncthreads(); }
    if (tid == 0) sbeta = sigm(red[0] + fb_b[0]);

    int cap = captions[sidx[b]*TTOK + t];
    if (tid < 128)
        xfb[(size_t)b*KX + q*128 + tid] = f2bf(emb_table[(size_t)cap*EM + q*128 + tid]);
    __syncthreads();

    float beta = sbeta;
    int e0 = q*512 + tid*2;
    const u16* pe = ebf + (size_t)b*LL*EE + e0;
    float ax = 0.f, ay = 0.f;
    for (int l = 0; l < LL; l++){
        unsigned u = *(const unsigned*)(pe + (size_t)l*EE);
        float a = alpha_s[l];
        ax += a * __uint_as_float(u << 16);
        ay += a * __uint_as_float(u & 0xFFFF0000u);
    }
    unsigned pk = (unsigned)f2bf(beta*ax) | ((unsigned)f2bf(beta*ay) << 16);
    *(unsigned*)(xfb + (size_t)b*KX + EM + e0) = pk;
}

// ---------------- per-step: gates MFMA (K-split x8, atomic into pre-seeded gacc) ----------------
__global__ void k_gates(const u16* __restrict__ Wb, const u16* __restrict__ xfb,
                        float* __restrict__ gacc){
    int tid = threadIdx.x, lane = tid & 63, w = tid >> 6;
    int lane15 = lane & 15, quad = lane >> 4;
    int n0 = blockIdx.x*64 + w*16;
    int kbase = blockIdx.y*384;
    const u16* bp = Wb + (size_t)(n0 + lane15)*KX + kbase + quad*8;
    const u16* ap = xfb + (size_t)lane15*KX + kbase + quad*8;
    f32x4 z = {0.f,0.f,0.f,0.f};
    f32x4 acc[4] = {z,z,z,z};
    #pragma unroll 4
    for (int kc = 0; kc < 12; kc++){
        bf16x8 bv = *(const bf16x8*)(bp + kc*32);
        bf16x8 a0 = *(const bf16x8*)(ap + kc*32);
        bf16x8 a1 = *(const bf16x8*)(ap + 16*KX + kc*32);
        bf16x8 a2 = *(const bf16x8*)(ap + 32*KX + kc*32);
        bf16x8 a3 = *(const bf16x8*)(ap + 48*KX + kc*32);
        acc[0] = MFMA16(a0, bv, acc[0]);
        acc[1] = MFMA16(a1, bv, acc[1]);
        acc[2] = MFMA16(a2, bv, acc[2]);
        acc[3] = MFMA16(a3, bv, acc[3]);
    }
    #pragma unroll
    for (int mt = 0; mt < 4; mt++)
        #pragma unroll
        for (int r = 0; r < 4; r++){
            int m = mt*16 + quad*4 + r;
            atomicAdd(&gacc[(size_t)m*G4 + n0 + lane15], acc[mt][r]);
        }
}

// ---------------- per-step: LSTM state update (+ reseed gacc with biases) ----------------
__global__ void k_update(float* __restrict__ gacc, const float* __restrict__ b_ih,
                         const float* __restrict__ b_hh, const int* __restrict__ dl,
                         u16* __restrict__ hb, float* __restrict__ c,
                         u16* __restrict__ xfb, int t){
    int gid = blockIdx.x*256 + threadIdx.x;
    int b = gid >> 9, d = gid & 511;
    size_t base = (size_t)b*G4 + d;
    float gi = gacc[base];
    float gf = gacc[base + 512];
    float gg = gacc[base + 1024];
    float go = gacc[base + 1536];
    float ig = sigm(gi), fg = sigm(gf), g = ftanh(gg), o = sigm(go);
    float cold = c[gid];
    float cn = fg*cold + ig*g;
    float hn = o*ftanh(cn);
    if (t < dl[b]){
        c[gid] = cn;
        u16 hv = f2bf(hn);
        hb[gid] = hv;
        xfb[(size_t)b*KX + 2560 + d] = hv;
    }
    gacc[base]        = b_ih[d]        + b_hh[d];
    gacc[base + 512]  = b_ih[d + 512]  + b_hh[d + 512];
    gacc[base + 1024] = b_ih[d + 1024] + b_hh[d + 1024];
    gacc[base + 1536] = b_ih[d + 1536] + b_hh[d + 1536];
}

// ---------------- per-step: fc prediction + next-step hU (MFMA) ----------------
__global__ void k_pred(const u16* __restrict__ fcWb, const float* __restrict__ fc_b,
                       const u16* __restrict__ Uab, const u16* __restrict__ hb,
                       const int* __restrict__ dl, float* __restrict__ out,
                       float* __restrict__ hU, int t, int hu_only){
    int tid = threadIdx.x, lane = tid & 63, w = tid >> 6;
    int lane15 = lane & 15, quad = lane >> 4;
    int bid = blockIdx.x;
    bool pred; int jc;
    if (hu_only){ pred = false; jc = bid; }
    else if (bid < 157){ pred = true; jc = bid; }
    else { pred = false; jc = bid - 157; }
    const u16* W = pred ? fcWb : Uab;
    int n0 = jc*64 + w*16;
    const u16* bp = W + (size_t)(n0 + lane15)*AD + quad*8;
    const u16* ap = hb + (size_t)lane15*AD + quad*8;
    f32x4 z = {0.f,0.f,0.f,0.f};
    f32x4 acc[4] = {z,z,z,z};
    #pragma unroll 4
    for (int kc = 0; kc < 16; kc++){
        bf16x8 bv = *(const bf16x8*)(bp + kc*32);
        bf16x8 a0 = *(const bf16x8*)(ap + kc*32);
        bf16x8 a1 = *(const bf16x8*)(ap + 16*AD + kc*32);
        bf16x8 a2 = *(const bf16x8*)(ap + 32*AD + kc*32);
        bf16x8 a3 = *(const bf16x8*)(ap + 48*AD + kc*32);
        acc[0] = MFMA16(a0, bv, acc[0]);
        acc[1] = MFMA16(a1, bv, acc[1]);
        acc[2] = MFMA16(a2, bv, acc[2]);
        acc[3] = MFMA16(a3, bv, acc[3]);
    }
    if (pred){
        int j = n0 + lane15;
        if (j < VV){
            float bias = fc_b[j];
            #pragma unroll
            for (int mt = 0; mt < 4; mt++)
                #pragma unroll
                for (int r = 0; r < 4; r++){
                    int b = mt*16 + quad*4 + r;
                    bool mk = t < dl[b];
                    out[OUT_PRED + ((size_t)b*MT + t)*VV + j] = mk ? acc[mt][r] + bias : 0.f;
                }
        }
    } else {
        int n = n0 + lane15;
        #pragma unroll
        for (int mt = 0; mt < 4; mt++)
            #pragma unroll
            for (int r = 0; r < 4; r++){
                int b = mt*16 + quad*4 + r;
                hU[(size_t)b*AD + n] = acc[mt][r];
            }
    }
}

extern "C" void kernel_launch(void* const* d_in, const int* in_sizes, int n_in,
                              void* d_out, int out_size, void* d_ws, size_t ws_size,
                              hipStream_t stream) {
    const float* enc       = (const float*)d_in[0];
    const int*   captions  = (const int*)d_in[1];
    const int*   lengths   = (const int*)d_in[2];
    const float* emb_table = (const float*)d_in[3];
    const float* W_a       = (const float*)d_in[4];
    const float* U_a       = (const float*)d_in[5];
    const float* w_att     = (const float*)d_in[6];
    const float* fb_W      = (const float*)d_in[7];
    const float* fb_b      = (const float*)d_in[8];
    const float* W_ih      = (const float*)d_in[9];
    const float* W_hh      = (const float*)d_in[10];
    const float* b_ih      = (const float*)d_in[11];
    const float* b_hh      = (const float*)d_in[12];
    const float* fc_W      = (const float*)d_in[13];
    const float* fc_b      = (const float*)d_in[14];
    const float* ih_W      = (const float*)d_in[15];
    const float* ih_b      = (const float*)d_in[16];
    const float* ic_W      = (const float*)d_in[17];
    const float* ic_b      = (const float*)d_in[18];

    float* out = (float*)d_out;
    float* ws  = (float*)d_ws;
    int* sidx = (int*)(ws + OFF_SIDX);
    int* dl   = (int*)(ws + OFF_DL);
    float* mean = ws + OFF_MEAN;
    float* c    = ws + OFF_C;
    float* hU   = ws + OFF_HU;
    float* en   = ws + OFF_ATT;
    float* gacc = ws + OFF_GACC;
    u16* hb   = (u16*)(ws + OFF_HB);
    u16* xfb  = (u16*)(ws + OFF_XFB);
    u16* Wb   = (u16*)(ws + OFF_WB);
    u16* fcWb = (u16*)(ws + OFF_FCWB);
    u16* Uab  = (u16*)(ws + OFF_UAB);
    u16* Wab  = (u16*)(ws + OFF_WAB);
    u16* Waeb = (u16*)(ws + OFF_WAEB);
    u16* ebf  = (u16*)(ws + OFF_EBF);
    u16* meanb = (u16*)(ws + OFF_MEANB);
    u16* ihb  = (u16*)(ws + OFF_IHB);
    u16* icb  = (u16*)(ws + OFF_ICB);

    k_sort<<<1, 64, 0, stream>>>(lengths, captions, out, sidx, dl);
    k_ginit<<<768, 256, 0, stream>>>(gacc, mean);
    k_meanbf<<<dim3(2, BB, 2), 256, 0, stream>>>(enc, sidx, mean, ebf);
    k_meanb<<<64, 256, 0, stream>>>(mean, meanb);
    k_tr<<<dim3(64, 16), dim3(32, 8), 0, stream>>>(ih_W, ihb, 2048, 512);
    k_tr<<<dim3(64, 16), dim3(32, 8), 0, stream>>>(ic_W, icb, 2048, 512);
    k_h0c0s<<<dim3(8, 2, 4), 256, 0, stream>>>(ihb, icb, meanb, gacc);
    k_h0c0f<<<512, 256, 0, stream>>>(gacc, ih_b, ic_b, b_ih, b_hh, hb, c, xfb);
    k_wb<<<dim3(12, G4), 256, 0, stream>>>(W_ih, W_hh, Wb);
    k_tr<<<dim3(16, 314), dim3(32, 8), 0, stream>>>(fc_W, fcWb, 512, VV);
    k_tr<<<dim3(16, 16),  dim3(32, 8), 0, stream>>>(U_a, Uab, 512, 512);
    k_tr<<<dim3(64, 16),  dim3(32, 8), 0, stream>>>(W_a, Wab, 2048, 512);
    k_waenc2<<<dim3(98, 4), 256, 0, stream>>>(ebf, Wab, Waeb);
    k_pred<<<8, 256, 0, stream>>>(fcWb, fc_b, Uab, hb, dl, out, hU, 0, 1);

    for (int t = 0; t < MT; t++){
        k_energyA<<<256, 256, 0, stream>>>(Waeb, hU, w_att, en);
        k_ctx<<<dim3(4, BB), 256, 0, stream>>>(en, ebf, hb, fb_W, fb_b,
                                               emb_table, captions, sidx, dl, xfb, out, t);
        k_gates<<<dim3(32, 8), 256, 0, stream>>>(Wb, xfb, gacc);
        k_update<<<128, 256, 0, stream>>>(gacc, b_ih, b_hh, dl, hb, c, xfb, t);
        k_pred<<<165, 256, 0, stream>>>(fcWb, fc_b, Uab, hb, dl, out, hU, t, 0);
    }
}